// Round 2
// baseline (277.203 us; speedup 1.0000x reference)
//
#include <hip/hip_runtime.h>
#include <hip/hip_bf16.h>

#define BB 64
#define TT 2048
#define DD 256
#define EPSF 1e-7f

typedef __attribute__((ext_vector_type(8))) short v8s;   // 8 x bf16 (4 VGPRs) — MFMA A/B frag
typedef __attribute__((ext_vector_type(4))) float v4f;   // MFMA C/D frag

__device__ __forceinline__ unsigned short f2bf_rne(float v) {
    union { float f; unsigned int u; } c;
    c.f = v;
    unsigned int lsb = (c.u >> 16) & 1u;
    return (unsigned short)((c.u + 0x7fffu + lsb) >> 16);
}

// exact identity tanh(x) = 1 - 2/(exp(2x)+1); __expf rel err ~1e-6
__device__ __forceinline__ float tanh_fast(float x) {
    float e = __expf(2.0f * x);
    return 1.0f - 2.0f / (e + 1.0f);
}

// ---------------- kernel 1: W[d][e] (fp32) -> Wt[e][d] (bf16) ----------------
__global__ __launch_bounds__(256) void pack_wt(const float* __restrict__ W,
                                               unsigned short* __restrict__ Wt) {
    int e = blockIdx.x;   // 0..255
    int d = threadIdx.x;  // 0..255
    Wt[(size_t)e * DD + d] = f2bf_rne(W[(size_t)d * DD + e]);
}

// ---------------- kernel 2: e[row] = sum_n tanh( (x@W)[row][n] + b[n] ) * uw[n] ----------------
// block = 256 threads = 4 waves; wave handles 32 rows (two 16-row m-tiles); block = 128 rows
__global__ __launch_bounds__(256) void gemm_e(const float* __restrict__ x,
                                              const unsigned short* __restrict__ Wt,
                                              const float* __restrict__ bias,
                                              const float* __restrict__ uw,
                                              float* __restrict__ e_out) {
    const int tid  = threadIdx.x;
    const int wave = tid >> 6;
    const int lane = tid & 63;
    const int quad = lane >> 4;   // 0..3
    const int m    = lane & 15;   // 0..15
    const long row_base = (long)blockIdx.x * 128 + wave * 32;

    // preload all A fragments for this wave's 32 rows (K=256 -> 8 k-steps of 32)
    // A layout (16x16x32): A[m = lane&15][k = quad*8 + j], j contiguous
    v8s afrag[2][8];
#pragma unroll
    for (int tile = 0; tile < 2; ++tile) {
        const float* rp = x + (row_base + tile * 16 + m) * DD + quad * 8;
#pragma unroll
        for (int ks = 0; ks < 8; ++ks) {
            float4 lo = *(const float4*)(rp + ks * 32);
            float4 hi = *(const float4*)(rp + ks * 32 + 4);
            v8s f;
            f[0] = (short)f2bf_rne(lo.x); f[1] = (short)f2bf_rne(lo.y);
            f[2] = (short)f2bf_rne(lo.z); f[3] = (short)f2bf_rne(lo.w);
            f[4] = (short)f2bf_rne(hi.x); f[5] = (short)f2bf_rne(hi.y);
            f[6] = (short)f2bf_rne(hi.z); f[7] = (short)f2bf_rne(hi.w);
            afrag[tile][ks] = f;
        }
    }

    float esum0[4] = {0.f, 0.f, 0.f, 0.f};
    float esum1[4] = {0.f, 0.f, 0.f, 0.f};

    for (int nt = 0; nt < 16; ++nt) {
        v4f acc0 = {0.f, 0.f, 0.f, 0.f};
        v4f acc1 = {0.f, 0.f, 0.f, 0.f};
        // B layout: B[k = quad*8+j][n = lane&15]; Wt[n][k] contiguous in k (bf16)
        const unsigned short* bp = Wt + (size_t)(nt * 16 + m) * DD + quad * 8;
#pragma unroll
        for (int ks = 0; ks < 8; ++ks) {
            v8s bfrag = *(const v8s*)(bp + ks * 32);
            acc0 = __builtin_amdgcn_mfma_f32_16x16x32_bf16(afrag[0][ks], bfrag, acc0, 0, 0, 0);
            acc1 = __builtin_amdgcn_mfma_f32_16x16x32_bf16(afrag[1][ks], bfrag, acc1, 0, 0, 0);
        }
        // C/D layout: col = lane&15 (= n within tile), row = quad*4 + reg
        int n = nt * 16 + m;
        float bb = bias[n];
        float un = uw[n];
#pragma unroll
        for (int r = 0; r < 4; ++r) {
            esum0[r] += tanh_fast(acc0[r] + bb) * un;
            esum1[r] += tanh_fast(acc1[r] + bb) * un;
        }
    }

    // reduce over the 16 lanes that share a row-set (xor of bits 0..3 stays in the quad group)
#pragma unroll
    for (int o = 1; o < 16; o <<= 1) {
#pragma unroll
        for (int r = 0; r < 4; ++r) {
            esum0[r] += __shfl_xor(esum0[r], o, 64);
            esum1[r] += __shfl_xor(esum1[r], o, 64);
        }
    }
    if (m == 0) {
#pragma unroll
        for (int r = 0; r < 4; ++r) {
            e_out[row_base + quad * 4 + r]      = esum0[r];
            e_out[row_base + 16 + quad * 4 + r] = esum1[r];
        }
    }
}

// ---------------- kernel 3: a[b,t] = exp(e)*mask / (sum_t exp(e)*mask + EPS) ----------------
// one block per batch; in-place over e buffer is safe (each slot read+written by same thread)
__global__ __launch_bounds__(256) void softmax_t(const float* e_in,
                                                 const int* __restrict__ mask,
                                                 float* a_out) {
    int b = blockIdx.x;
    int tid = threadIdx.x;
    int lane = tid & 63, wave = tid >> 6;
    float p[8];
    float s = 0.f;
#pragma unroll
    for (int i = 0; i < 8; ++i) {
        int t = i * 256 + tid;
        float pm = __expf(e_in[b * TT + t]) * (float)mask[b * TT + t];
        p[i] = pm;
        s += pm;
    }
#pragma unroll
    for (int o = 1; o < 64; o <<= 1) s += __shfl_xor(s, o, 64);
    __shared__ float red[4];
    if (lane == 0) red[wave] = s;
    __syncthreads();
    float inv = 1.0f / (red[0] + red[1] + red[2] + red[3] + EPSF);
#pragma unroll
    for (int i = 0; i < 8; ++i) a_out[b * TT + i * 256 + tid] = p[i] * inv;
}

// ---------------- kernel 4: out[b,d] += sum_t x[b,t,d] * a[b,t]  (fp32 atomics into d_out) ----
// grid = 64 batches * 16 T-chunks of 128; block 256 = 4 t-groups x 64 d-quads
__global__ __launch_bounds__(256) void wsum(const float* __restrict__ x,
                                            const float* __restrict__ a,
                                            float* __restrict__ out) {
    int b = blockIdx.x >> 4;
    int chunk = blockIdx.x & 15;
    int g  = threadIdx.x >> 6;  // 0..3  (t mod 4)
    int dq = threadIdx.x & 63;  // 0..63 (4 d's each)
    float acc[4] = {0.f, 0.f, 0.f, 0.f};
#pragma unroll 4
    for (int i = 0; i < 32; ++i) {
        int t = chunk * 128 + g + i * 4;
        float aw = a[b * TT + t];
        float4 xv = *(const float4*)(x + ((size_t)(b * TT + t)) * DD + dq * 4);
        acc[0] += aw * xv.x;
        acc[1] += aw * xv.y;
        acc[2] += aw * xv.z;
        acc[3] += aw * xv.w;
    }
    __shared__ float red[4][DD];
    ((float4*)red[g])[dq] = make_float4(acc[0], acc[1], acc[2], acc[3]);
    __syncthreads();
    int d = threadIdx.x;  // 0..255
    float s2 = red[0][d] + red[1][d] + red[2][d] + red[3][d];
    atomicAdd(&out[b * DD + d], s2);
}

extern "C" void kernel_launch(void* const* d_in, const int* in_sizes, int n_in,
                              void* d_out, int out_size, void* d_ws, size_t ws_size,
                              hipStream_t stream) {
    const float* x    = (const float*)d_in[0];  // [64,2048,256] fp32 (bf16-rounded values)
    const float* W    = (const float*)d_in[1];  // [256,256] fp32
    const float* bias = (const float*)d_in[2];  // [256] fp32 (zeros)
    const float* uw   = (const float*)d_in[3];  // [256] fp32
    const int*   mask = (const int*)d_in[4];    // [64,2048] int32
    float*       out  = (float*)d_out;          // [64,256] fp32

    char* ws = (char*)d_ws;
    unsigned short* Wt = (unsigned short*)ws;       // 128 KB bf16 W^T
    float* e_buf       = (float*)(ws + 131072);     // 512 KB (reused in-place for a)
    // total ws use: 655360 bytes

    pack_wt<<<dim3(256), dim3(256), 0, stream>>>(W, Wt);
    gemm_e<<<dim3(1024), dim3(256), 0, stream>>>(x, Wt, bias, uw, e_buf);
    softmax_t<<<dim3(64), dim3(256), 0, stream>>>(e_buf, mask, e_buf);
    hipMemsetAsync(out, 0, (size_t)out_size * sizeof(float), stream);
    wsum<<<dim3(1024), dim3(256), 0, stream>>>(x, e_buf, out);
}

// Round 3
// 276.981 us; speedup vs baseline: 1.0008x; 1.0008x over previous
//
#include <hip/hip_runtime.h>
#include <hip/hip_bf16.h>

#define BB 64
#define TT 2048
#define DD 256
#define EPSF 1e-7f

typedef __attribute__((ext_vector_type(8))) short v8s;   // 8 x bf16 (4 VGPRs) — MFMA A/B frag
typedef __attribute__((ext_vector_type(4))) float v4f;   // MFMA C/D frag

__device__ __forceinline__ unsigned int pack2_bf16(float a, float b) {
    union { __hip_bfloat162 h; unsigned int u; } c;
    c.h = __float22bfloat162_rn(make_float2(a, b));   // v_cvt_pk_bf16_f32, RNE
    return c.u;
}

// exact identity tanh(x) = 1 - 2/(exp(2x)+1); __expf rel err ~1e-6
__device__ __forceinline__ float tanh_fast(float x) {
    float e = __expf(2.0f * x);
    return 1.0f - 2.0f / (e + 1.0f);
}

// ---------------- kernel 1: W[d][e] (fp32) -> Wt[e][d] (bf16), LDS tile transpose ----------------
// 64 blocks, each transposes a 32x32 tile. Reads and writes are segment-coalesced.
__global__ __launch_bounds__(256) void pack_wt(const float* __restrict__ W,
                                               unsigned short* __restrict__ Wt) {
    __shared__ float tile[32][33];   // +1 pad breaks bank conflicts on transposed read
    int bx = blockIdx.x & 7;    // d-tile index
    int by = blockIdx.x >> 3;   // e-tile index
    int r  = threadIdx.x >> 3;        // 0..31
    int c4 = (threadIdx.x & 7) * 4;   // 0,4,...,28
    float4 v = *(const float4*)(W + (size_t)(bx * 32 + r) * DD + by * 32 + c4);
    tile[r][c4 + 0] = v.x; tile[r][c4 + 1] = v.y;
    tile[r][c4 + 2] = v.z; tile[r][c4 + 3] = v.w;
    __syncthreads();
    // write Wt[e][d], e = by*32 + r, d = bx*32 + c4..c4+3
    float a0 = tile[c4 + 0][r], a1 = tile[c4 + 1][r];
    float a2 = tile[c4 + 2][r], a3 = tile[c4 + 3][r];
    uint2 pp = make_uint2(pack2_bf16(a0, a1), pack2_bf16(a2, a3));
    *(uint2*)(Wt + (size_t)(by * 32 + r) * DD + bx * 32 + c4) = pp;
}

// ---------------- kernel 2: e[row] = sum_n tanh( (x@W)[row][n] + b[n] ) * uw[n] ----------------
// block = 256 threads = 4 waves; wave handles 32 rows (two 16-row m-tiles); block = 128 rows.
// x tile staged through LDS (coalesced fp32 loads, packed to bf16 in-register).
__global__ __launch_bounds__(256) void gemm_e(const float* __restrict__ x,
                                              const unsigned short* __restrict__ Wt,
                                              const float* __restrict__ bias,
                                              const float* __restrict__ uw,
                                              float* __restrict__ e_out) {
    __shared__ unsigned short xs[128][256];   // 64 KB bf16 tile
    const int tid  = threadIdx.x;
    const int wave = tid >> 6;
    const int lane = tid & 63;
    const int quad = lane >> 4;   // 0..3
    const int m    = lane & 15;   // 0..15
    const long row_base = (long)blockIdx.x * 128;

    // ---- stage: wave w loads rows w*32..w*32+31; each row = 64 lanes x float4 = 1 KB coalesced
    {
        const float* gp = x + (row_base + wave * 32) * (long)DD + lane * 4;
        unsigned short* sp = &xs[wave * 32][lane * 4];
#pragma unroll 8
        for (int r = 0; r < 32; ++r) {
            float4 v = *(const float4*)(gp + (long)r * DD);
            uint2 pp = make_uint2(pack2_bf16(v.x, v.y), pack2_bf16(v.z, v.w));
            *(uint2*)(sp + (size_t)r * 256) = pp;
        }
    }
    __syncthreads();

    // ---- A fragments from LDS: A[m = lane&15][k = quad*8 + j]
    v8s afrag[2][8];
#pragma unroll
    for (int tile = 0; tile < 2; ++tile) {
        const unsigned short* rp = &xs[wave * 32 + tile * 16 + m][quad * 8];
#pragma unroll
        for (int ks = 0; ks < 8; ++ks) {
            afrag[tile][ks] = *(const v8s*)(rp + ks * 32);
        }
    }

    float esum0[4] = {0.f, 0.f, 0.f, 0.f};
    float esum1[4] = {0.f, 0.f, 0.f, 0.f};

    for (int nt = 0; nt < 16; ++nt) {
        v4f acc0 = {0.f, 0.f, 0.f, 0.f};
        v4f acc1 = {0.f, 0.f, 0.f, 0.f};
        // B layout: B[k = quad*8+j][n = lane&15]; Wt[n][k] contiguous in k (bf16)
        const unsigned short* bp = Wt + (size_t)(nt * 16 + m) * DD + quad * 8;
#pragma unroll
        for (int ks = 0; ks < 8; ++ks) {
            v8s bfrag = *(const v8s*)(bp + ks * 32);
            acc0 = __builtin_amdgcn_mfma_f32_16x16x32_bf16(afrag[0][ks], bfrag, acc0, 0, 0, 0);
            acc1 = __builtin_amdgcn_mfma_f32_16x16x32_bf16(afrag[1][ks], bfrag, acc1, 0, 0, 0);
        }
        // C/D layout: col = lane&15 (= n within tile), row = quad*4 + reg
        int n = nt * 16 + m;
        float bb = bias[n];
        float un = uw[n];
#pragma unroll
        for (int r = 0; r < 4; ++r) {
            esum0[r] += tanh_fast(acc0[r] + bb) * un;
            esum1[r] += tanh_fast(acc1[r] + bb) * un;
        }
    }

    // reduce over the 16 lanes (n) sharing each output-row set
#pragma unroll
    for (int o = 1; o < 16; o <<= 1) {
#pragma unroll
        for (int r = 0; r < 4; ++r) {
            esum0[r] += __shfl_xor(esum0[r], o, 64);
            esum1[r] += __shfl_xor(esum1[r], o, 64);
        }
    }
    if (m == 0) {
        const long wrow = row_base + wave * 32;
#pragma unroll
        for (int r = 0; r < 4; ++r) {
            e_out[wrow + quad * 4 + r]      = esum0[r];
            e_out[wrow + 16 + quad * 4 + r] = esum1[r];
        }
    }
}

// ---------------- kernel 3: a[b,t] = exp(e)*mask / (sum_t exp(e)*mask + EPS) ----------------
__global__ __launch_bounds__(256) void softmax_t(const float* e_in,
                                                 const int* __restrict__ mask,
                                                 float* a_out) {
    int b = blockIdx.x;
    int tid = threadIdx.x;
    int lane = tid & 63, wave = tid >> 6;
    float p[8];
    float s = 0.f;
#pragma unroll
    for (int i = 0; i < 8; ++i) {
        int t = i * 256 + tid;
        float pm = __expf(e_in[b * TT + t]) * (float)mask[b * TT + t];
        p[i] = pm;
        s += pm;
    }
#pragma unroll
    for (int o = 1; o < 64; o <<= 1) s += __shfl_xor(s, o, 64);
    __shared__ float red[4];
    if (lane == 0) red[wave] = s;
    __syncthreads();
    float inv = 1.0f / (red[0] + red[1] + red[2] + red[3] + EPSF);
#pragma unroll
    for (int i = 0; i < 8; ++i) a_out[b * TT + i * 256 + tid] = p[i] * inv;
}

// ---------------- kernel 4: out[b,d] += sum_t x[b,t,d] * a[b,t]  (fp32 atomics into d_out) ----
// grid = 64 batches * 16 T-chunks of 128; block 256 = 4 t-groups x 64 d-quads.
// Two interleaved t-streams + unroll-4 -> 8 float4 loads in flight per thread.
__global__ __launch_bounds__(256) void wsum(const float* __restrict__ x,
                                            const float* __restrict__ a,
                                            float* __restrict__ out) {
    int b = blockIdx.x >> 4;
    int chunk = blockIdx.x & 15;
    int g  = threadIdx.x >> 6;  // 0..3  (t mod 4)
    int dq = threadIdx.x & 63;  // 0..63 (4 d's each)
    const float* xb = x + ((size_t)b * TT + chunk * 128 + g) * DD + dq * 4;
    const float* ab = a + b * TT + chunk * 128 + g;
    float acc0[4] = {0.f, 0.f, 0.f, 0.f};
    float acc1[4] = {0.f, 0.f, 0.f, 0.f};
#pragma unroll 4
    for (int i = 0; i < 16; ++i) {
        float aw0 = ab[i * 8];
        float aw1 = ab[i * 8 + 4];
        float4 x0 = *(const float4*)(xb + (size_t)(i * 8) * DD);
        float4 x1 = *(const float4*)(xb + (size_t)(i * 8 + 4) * DD);
        acc0[0] += aw0 * x0.x; acc0[1] += aw0 * x0.y;
        acc0[2] += aw0 * x0.z; acc0[3] += aw0 * x0.w;
        acc1[0] += aw1 * x1.x; acc1[1] += aw1 * x1.y;
        acc1[2] += aw1 * x1.z; acc1[3] += aw1 * x1.w;
    }
    __shared__ float red[4][DD];
    ((float4*)red[g])[dq] = make_float4(acc0[0] + acc1[0], acc0[1] + acc1[1],
                                        acc0[2] + acc1[2], acc0[3] + acc1[3]);
    __syncthreads();
    int d = threadIdx.x;  // 0..255
    float s2 = red[0][d] + red[1][d] + red[2][d] + red[3][d];
    atomicAdd(&out[b * DD + d], s2);
}

extern "C" void kernel_launch(void* const* d_in, const int* in_sizes, int n_in,
                              void* d_out, int out_size, void* d_ws, size_t ws_size,
                              hipStream_t stream) {
    const float* x    = (const float*)d_in[0];  // [64,2048,256] fp32 (bf16-rounded values)
    const float* W    = (const float*)d_in[1];  // [256,256] fp32
    const float* bias = (const float*)d_in[2];  // [256] fp32
    const float* uw   = (const float*)d_in[3];  // [256] fp32
    const int*   mask = (const int*)d_in[4];    // [64,2048] int32
    float*       out  = (float*)d_out;          // [64,256] fp32

    char* ws = (char*)d_ws;
    unsigned short* Wt = (unsigned short*)ws;       // 128 KB bf16 W^T
    float* e_buf       = (float*)(ws + 131072);     // 512 KB (reused in-place for a)
    // total ws use: 655360 bytes

    pack_wt<<<dim3(64), dim3(256), 0, stream>>>(W, Wt);
    gemm_e<<<dim3(1024), dim3(256), 0, stream>>>(x, Wt, bias, uw, e_buf);
    softmax_t<<<dim3(64), dim3(256), 0, stream>>>(e_buf, mask, e_buf);
    hipMemsetAsync(out, 0, (size_t)out_size * sizeof(float), stream);
    wsum<<<dim3(1024), dim3(256), 0, stream>>>(x, e_buf, out);
}

// Round 4
// 233.827 us; speedup vs baseline: 1.1855x; 1.1846x over previous
//
#include <hip/hip_runtime.h>
#include <hip/hip_bf16.h>

#define BB 64
#define TT 2048
#define DD 256
#define EPSF 1e-7f
#define XS_STRIDE 264   // shorts/row: 528 B = 33*16 B -> 16B-aligned b128, near-floor bank spread

typedef __attribute__((ext_vector_type(8))) short v8s;   // 8 x bf16 (4 VGPRs) — MFMA A/B frag
typedef __attribute__((ext_vector_type(4))) float v4f;   // MFMA C/D frag

__device__ __forceinline__ float bf2f(unsigned short u) {
    union { unsigned int i; float f; } c;
    c.i = ((unsigned int)u) << 16;
    return c.f;
}

__device__ __forceinline__ unsigned int pack2_bf16(float a, float b) {
    union { __hip_bfloat162 h; unsigned int u; } c;
    c.h = __float22bfloat162_rn(make_float2(a, b));   // v_cvt_pk_bf16_f32, RNE
    return c.u;
}

// exact identity tanh(x) = 1 - 2/(exp(2x)+1); saturates correctly at +-inf
__device__ __forceinline__ float tanh_fast(float x) {
    float e = __expf(2.0f * x);
    return 1.0f - 2.0f / (e + 1.0f);
}

// ---------------- kernel 1: W[d][e] (fp32) -> Wt[e][d] (bf16), LDS tile transpose ----------------
__global__ __launch_bounds__(256) void pack_wt(const float* __restrict__ W,
                                               unsigned short* __restrict__ Wt) {
    __shared__ float tile[32][33];
    int bx = blockIdx.x & 7;    // d-tile
    int by = blockIdx.x >> 3;   // e-tile
    int r  = threadIdx.x >> 3;        // 0..31
    int c4 = (threadIdx.x & 7) * 4;   // 0,4,...,28
    float4 v = *(const float4*)(W + (size_t)(bx * 32 + r) * DD + by * 32 + c4);
    tile[r][c4 + 0] = v.x; tile[r][c4 + 1] = v.y;
    tile[r][c4 + 2] = v.z; tile[r][c4 + 3] = v.w;
    __syncthreads();
    float a0 = tile[c4 + 0][r], a1 = tile[c4 + 1][r];
    float a2 = tile[c4 + 2][r], a3 = tile[c4 + 3][r];
    uint2 pp = make_uint2(pack2_bf16(a0, a1), pack2_bf16(a2, a3));
    *(uint2*)(Wt + (size_t)(by * 32 + r) * DD + bx * 32 + c4) = pp;
}

// ---------------- kernel 2: fused e-GEMM + tanh·uw + exp·mask + weighted partial sum ----------
// One block = 64 consecutive rows (t's of one batch; 2048 % 64 == 0 so no batch crossing).
// Phase 1: stage x tile (bf16) in LDS.  Phase 2: e via MFMA, nt split across waves.
// Phase 3/4: reduce e, p = exp(e)*mask, block denominator.  Phase 5: num[d] = sum_t p_t*x[t][d].
__global__ __launch_bounds__(256) void fused_att(const float* __restrict__ x,
                                                 const unsigned short* __restrict__ Wt,
                                                 const float* __restrict__ bias,
                                                 const float* __restrict__ uw,
                                                 const int* __restrict__ mask,
                                                 float* __restrict__ numpart,
                                                 float* __restrict__ denpart) {
    __shared__ unsigned short xs[64 * XS_STRIDE];   // 33.75 KB bf16 tile
    __shared__ float ered[4][64];
    __shared__ float pshared[64];

    const int tid  = threadIdx.x;
    const int wave = tid >> 6;
    const int lane = tid & 63;
    const int quad = lane >> 4;   // 0..3
    const int m    = lane & 15;   // 0..15
    const long rowbase = (long)blockIdx.x * 64;

    // hoisted per-wave bias/uw (n = nt*16 + m, nt = wave*4 + i)
    float bias_r[4], uw_r[4];
#pragma unroll
    for (int i = 0; i < 4; ++i) {
        int n = (wave * 4 + i) * 16 + m;
        bias_r[i] = bias[n];
        uw_r[i]   = uw[n];
    }

    // ---- phase 1: stage. wave w loads rows w*16..w*16+15; 1 KB coalesced per instruction
    {
        const float* gp = x + (rowbase + wave * 16) * (long)DD + lane * 4;
        unsigned short* sp = xs + (size_t)(wave * 16) * XS_STRIDE + lane * 4;
#pragma unroll
        for (int r = 0; r < 16; ++r) {
            float4 v = *(const float4*)(gp + (long)r * DD);
            uint2 pp = make_uint2(pack2_bf16(v.x, v.y), pack2_bf16(v.z, v.w));
            *(uint2*)(sp + (size_t)r * XS_STRIDE) = pp;
        }
    }
    __syncthreads();

    // ---- phase 2: wave w computes nt = 4w..4w+3 over all 4 m-tiles
    float esum[4][4];   // [mt][r], rows mt*16 + quad*4 + r, partial over this wave's n-range
#pragma unroll
    for (int mt = 0; mt < 4; ++mt)
#pragma unroll
        for (int r = 0; r < 4; ++r) esum[mt][r] = 0.f;

#pragma unroll
    for (int i = 0; i < 4; ++i) {
        const int nt = wave * 4 + i;
        const unsigned short* bp = Wt + (size_t)(nt * 16 + m) * DD + quad * 8;
        v8s bfrag[8];
#pragma unroll
        for (int ks = 0; ks < 8; ++ks) bfrag[ks] = *(const v8s*)(bp + ks * 32);
#pragma unroll
        for (int mt = 0; mt < 4; ++mt) {
            const unsigned short* ap = xs + (size_t)(mt * 16 + m) * XS_STRIDE + quad * 8;
            v4f acc = {0.f, 0.f, 0.f, 0.f};
#pragma unroll
            for (int ks = 0; ks < 8; ++ks) {
                v8s af = *(const v8s*)(ap + ks * 32);
                acc = __builtin_amdgcn_mfma_f32_16x16x32_bf16(af, bfrag[ks], acc, 0, 0, 0);
            }
#pragma unroll
            for (int r = 0; r < 4; ++r)
                esum[mt][r] += tanh_fast(acc[r] + bias_r[i]) * uw_r[i];
        }
    }

    // ---- phase 3: reduce over the 16 n-lanes; m==0 lanes hold e-partials for 16 rows each
#pragma unroll
    for (int o = 1; o < 16; o <<= 1)
#pragma unroll
        for (int mt = 0; mt < 4; ++mt)
#pragma unroll
            for (int r = 0; r < 4; ++r)
                esum[mt][r] += __shfl_xor(esum[mt][r], o, 64);
    if (m == 0) {
#pragma unroll
        for (int mt = 0; mt < 4; ++mt)
#pragma unroll
            for (int r = 0; r < 4; ++r)
                ered[wave][mt * 16 + quad * 4 + r] = esum[mt][r];
    }
    __syncthreads();

    // ---- phase 4: p_t = exp(e_t) * mask_t; block denominator partial (wave 0 only)
    if (tid < 64) {
        float e = ered[0][tid] + ered[1][tid] + ered[2][tid] + ered[3][tid];
        float p = __expf(e) * (float)mask[rowbase + tid];
        pshared[tid] = p;
        float s = p;
#pragma unroll
        for (int o = 1; o < 64; o <<= 1) s += __shfl_xor(s, o, 64);
        if (tid == 0) denpart[blockIdx.x] = s;
    }
    __syncthreads();

    // ---- phase 5: num[d] = sum_{t=0..63} p_t * x[t][d]  (x from LDS, p broadcast)
    float num = 0.f;
#pragma unroll 8
    for (int t = 0; t < 64; ++t) {
        num += pshared[t] * bf2f(xs[(size_t)t * XS_STRIDE + tid]);
    }
    numpart[(size_t)blockIdx.x * DD + tid] = num;
}

// ---------------- kernel 3: out[b][d] = sum_c num[b*32+c][d] / (sum_c den[b*32+c] + EPS) ------
__global__ __launch_bounds__(256) void finalize(const float* __restrict__ numpart,
                                                const float* __restrict__ denpart,
                                                float* __restrict__ out) {
    __shared__ float dsh;
    int b = blockIdx.x, d = threadIdx.x;
    if (d == 0) {
        float s = 0.f;
        for (int c = 0; c < 32; ++c) s += denpart[b * 32 + c];
        dsh = s + EPSF;
    }
    __syncthreads();
    float s = 0.f;
#pragma unroll
    for (int c = 0; c < 32; ++c) s += numpart[(size_t)(b * 32 + c) * DD + d];
    out[(size_t)b * DD + d] = s / dsh;
}

extern "C" void kernel_launch(void* const* d_in, const int* in_sizes, int n_in,
                              void* d_out, int out_size, void* d_ws, size_t ws_size,
                              hipStream_t stream) {
    const float* x    = (const float*)d_in[0];  // [64,2048,256] fp32 (bf16-rounded values)
    const float* W    = (const float*)d_in[1];  // [256,256] fp32
    const float* bias = (const float*)d_in[2];  // [256] fp32
    const float* uw   = (const float*)d_in[3];  // [256] fp32
    const int*   mask = (const int*)d_in[4];    // [64,2048] int32
    float*       out  = (float*)d_out;          // [64,256] fp32

    char* ws = (char*)d_ws;
    unsigned short* Wt = (unsigned short*)ws;            // 128 KB bf16 W^T
    float* numpart     = (float*)(ws + 131072);          // 2048*256*4 = 2 MB
    float* denpart     = (float*)(ws + 131072 + 2097152);// 8 KB
    // total ws use: ~2.23 MB

    pack_wt<<<dim3(64), dim3(256), 0, stream>>>(W, Wt);
    fused_att<<<dim3(2048), dim3(256), 0, stream>>>(x, Wt, bias, uw, mask, numpart, denpart);
    finalize<<<dim3(64), dim3(256), 0, stream>>>(numpart, denpart, out);
}